// Round 10
// baseline (461.943 us; speedup 1.0000x reference)
//
#include <hip/hip_runtime.h>

typedef float f4v __attribute__((ext_vector_type(4)));
typedef short s8v __attribute__((ext_vector_type(8)));
typedef float fv4 __attribute__((ext_vector_type(4)));
typedef unsigned short usv4 __attribute__((ext_vector_type(4)));

__device__ __forceinline__ unsigned short f2bf(float x){
  union { float f; unsigned u; } v; v.f = x;
  unsigned r = v.u + 0x7fffu + ((v.u >> 16) & 1u);
  return (unsigned short)(r >> 16);
}
__device__ __forceinline__ float bf2f(unsigned short b){
  union { unsigned u; float f; } v; v.u = ((unsigned)b) << 16;
  return v.f;
}
// split 8 consecutive f32 into hi/lo bf16 fragments
__device__ __forceinline__ void split8(const float* __restrict__ p, s8v& h, s8v& l){
  float4 v0 = *reinterpret_cast<const float4*>(p);
  float4 v1 = *reinterpret_cast<const float4*>(p + 4);
  float a[8] = {v0.x, v0.y, v0.z, v0.w, v1.x, v1.y, v1.z, v1.w};
#pragma unroll
  for (int j = 0; j < 8; ++j) {
    unsigned short hi = f2bf(a[j]);
    h[j] = (short)hi;
    l[j] = (short)f2bf(a[j] - bf2f(hi));
  }
}
__device__ __forceinline__ void zero8(s8v& v){
#pragma unroll
  for (int j = 0; j < 8; ++j) v[j] = 0;
}

// ---------------------------------------------------------------------------
// prep: Mt = 0.1*A^T ; Tp0 = I + Mt/4 (Taylor-4 innermost) ;
//       Bt[n][k]=B[k][n] bf16 ; Ct[j][n]=C[n][j] bf16
__global__ void k_prep(const float* __restrict__ A, const float* __restrict__ B,
                       const float* __restrict__ C,
                       float* __restrict__ Mt, float* __restrict__ Tp0,
                       unsigned short* __restrict__ Bt, unsigned short* __restrict__ Ct){
  int i = blockIdx.x * 256 + threadIdx.x;
  const int tot = 65536 + 262144 + 262144;
  for (; i < tot; i += gridDim.x * 256) {
    if (i < 65536) {
      int r = i >> 8, c = i & 255;
      float m = 0.1f * A[c * 256 + r];
      Mt[i] = m;
      Tp0[i] = m * 0.25f + (r == c ? 1.0f : 0.0f);
    } else if (i < 65536 + 262144) {
      int j = i - 65536;            // n*1024 + k
      int n = j >> 10, k = j & 1023;
      Bt[j] = f2bf(B[k * 256 + n]);
    } else {
      int j = i - 65536 - 262144;   // col*256 + n
      int col = j >> 8, n = j & 255;
      Ct[j] = f2bf(C[n * 1024 + col]);
    }
  }
}

// ---------------------------------------------------------------------------
// Taylor phase (one of 3): out = alpha*(Mt @ Bsrc) + I. grid = 16 blocks.
// final phase writes QS[0] (hi/lo bf16) and Et = Q1 - I instead of f32 out.
__global__ __launch_bounds__(256) void k_taylor(const float* __restrict__ Mt,
    const float* __restrict__ Bsrc, float* __restrict__ Odst,
    unsigned short* __restrict__ QSh, unsigned short* __restrict__ QSl,
    unsigned short* __restrict__ Et, float alpha, int fin){
  __shared__ unsigned short Bh[64][40], Bl[64][40];
  int tid = threadIdx.x, lane = tid & 63, w = tid >> 6;
  int wr = w >> 1, wc = w & 1, l15 = lane & 15, quad = lane >> 4, q8 = quad * 8;
  int bid = blockIdx.x;
  int m0 = (bid >> 2) * 64, n0 = (bid & 3) * 64;
  f4v acc[2][2] = {};
  for (int kt = 0; kt < 256; kt += 32) {
    __syncthreads();
    {
      int col = tid & 63, kk0 = (tid >> 6) * 8;
#pragma unroll
      for (int j = 0; j < 8; ++j) {
        float v = Bsrc[(kt + kk0 + j) * 256 + n0 + col];
        unsigned short hi = f2bf(v);
        Bh[col][kk0 + j] = hi;
        Bl[col][kk0 + j] = f2bf(v - bf2f(hi));
      }
    }
    __syncthreads();
#pragma unroll
    for (int aq = 0; aq < 2; ++aq) {
      s8v ah, al;
      split8(&Mt[(m0 + wr * 32 + aq * 16 + l15) * 256 + kt + q8], ah, al);
#pragma unroll
      for (int bq = 0; bq < 2; ++bq) {
        s8v bh = *reinterpret_cast<const s8v*>(&Bh[wc * 32 + bq * 16 + l15][q8]);
        s8v bl = *reinterpret_cast<const s8v*>(&Bl[wc * 32 + bq * 16 + l15][q8]);
        acc[aq][bq] = __builtin_amdgcn_mfma_f32_16x16x32_bf16(ah, bh, acc[aq][bq], 0, 0, 0);
        acc[aq][bq] = __builtin_amdgcn_mfma_f32_16x16x32_bf16(ah, bl, acc[aq][bq], 0, 0, 0);
        acc[aq][bq] = __builtin_amdgcn_mfma_f32_16x16x32_bf16(al, bh, acc[aq][bq], 0, 0, 0);
      }
    }
  }
#pragma unroll
  for (int aq = 0; aq < 2; ++aq)
#pragma unroll
    for (int bq = 0; bq < 2; ++bq)
#pragma unroll
      for (int r = 0; r < 4; ++r) {
        int gm = m0 + wr * 32 + aq * 16 + quad * 4 + r;
        int gn = n0 + wc * 32 + bq * 16 + l15;
        float raw = alpha * acc[aq][bq][r];
        float v = raw + (gm == gn ? 1.0f : 0.0f);
        if (!fin) {
          Odst[gm * 256 + gn] = v;
        } else {
          unsigned short hi = f2bf(v);
          QSh[gm * 256 + gn] = hi;
          QSl[gm * 256 + gn] = f2bf(v - bf2f(hi));
          Et[gm * 256 + gn] = f2bf(raw);   // Q1 - I
        }
      }
}

// ---------------------------------------------------------------------------
// power-stack doubling phase (one of 4 launches, d in {1,2,4,8}):
// QS[d+j] = QS[j] @ QS[d-1], j<d. grid = d*16 blocks. All tiles independent.
__global__ __launch_bounds__(256) void k_power(unsigned short* __restrict__ QSh,
    unsigned short* __restrict__ QSl, int d){
  __shared__ unsigned short Bh[64][40], Bl[64][40];
  int tid = threadIdx.x, lane = tid & 63, w = tid >> 6;
  int wr = w >> 1, wc = w & 1, l15 = lane & 15, quad = lane >> 4, q8 = quad * 8;
  int bid = blockIdx.x;
  int mt = bid >> 2, nt = bid & 3;
  int m0 = mt * 64, n0 = nt * 64;
  int bro = (d - 1) * 256;
  f4v acc[2][2] = {};
  for (int kt = 0; kt < 256; kt += 32) {
    __syncthreads();
    {
      int col = tid & 63, kk0 = (tid >> 6) * 8;
#pragma unroll
      for (int j = 0; j < 8; ++j) {
        int k = kt + kk0 + j;
        Bh[col][kk0 + j] = QSh[(bro + k) * 256 + n0 + col];
        Bl[col][kk0 + j] = QSl[(bro + k) * 256 + n0 + col];
      }
    }
    __syncthreads();
#pragma unroll
    for (int aq = 0; aq < 2; ++aq) {
      s8v ah = *reinterpret_cast<const s8v*>(&QSh[(m0 + wr * 32 + aq * 16 + l15) * 256 + kt + q8]);
      s8v al = *reinterpret_cast<const s8v*>(&QSl[(m0 + wr * 32 + aq * 16 + l15) * 256 + kt + q8]);
#pragma unroll
      for (int bq = 0; bq < 2; ++bq) {
        s8v bh = *reinterpret_cast<const s8v*>(&Bh[wc * 32 + bq * 16 + l15][q8]);
        s8v bl = *reinterpret_cast<const s8v*>(&Bl[wc * 32 + bq * 16 + l15][q8]);
        acc[aq][bq] = __builtin_amdgcn_mfma_f32_16x16x32_bf16(ah, bh, acc[aq][bq], 0, 0, 0);
        acc[aq][bq] = __builtin_amdgcn_mfma_f32_16x16x32_bf16(ah, bl, acc[aq][bq], 0, 0, 0);
        acc[aq][bq] = __builtin_amdgcn_mfma_f32_16x16x32_bf16(al, bh, acc[aq][bq], 0, 0, 0);
      }
    }
  }
#pragma unroll
  for (int aq = 0; aq < 2; ++aq)
#pragma unroll
    for (int bq = 0; bq < 2; ++bq)
#pragma unroll
      for (int r = 0; r < 4; ++r) {
        int gm = m0 + wr * 32 + aq * 16 + quad * 4 + r;
        int gn = n0 + wc * 32 + bq * 16 + l15;
        float v = acc[aq][bq][r];
        unsigned short hi = f2bf(v);
        QSh[(d * 256 + gm) * 256 + gn] = hi;
        QSl[(d * 256 + gm) * 256 + gn] = f2bf(v - bf2f(hi));
      }
}

// ---------------------------------------------------------------------------
// u_bf16 = bf16(x @ B) : M=16384, K=1024, N=256. grid = 512 blocks.
// Block = 32 m x 256 n, LDS double-buffered. x loads NON-TEMPORAL (zero
// reuse -> don't evict Bt from L2); Bt loads cached (L2-resident).
// u stores non-temporal.
__global__ __launch_bounds__(256) void k_gemm_u(const float* __restrict__ x,
                                                const unsigned short* __restrict__ Bt,
                                                unsigned short* __restrict__ u){
  // per buffer: Btile 256x40 shorts (offset 0), Atile 32x40 shorts (offset 10240)
  __shared__ unsigned short lds[2][256 * 40 + 32 * 40];
  int tid = threadIdx.x;
  int m0 = blockIdx.x * 32;
  int w = tid >> 6, lane = tid & 63;
  int l15 = lane & 15, quad = lane >> 4, q8 = quad * 8;
  // staging assignment
  int xrow = tid >> 3, xcol = (tid & 7) * 4;            // x: 32 rows x 8 thr/row
  const float* xsrc = x + (size_t)(m0 + xrow) * 1024 + xcol;
  const unsigned short* bsrc = Bt + (size_t)tid * 1024; // Bt row tid, 64B/chunk
  f4v acc[4][2] = {};   // [nq][mq]
  fv4 xr;
  uint4 br[4];
  // prologue: stage chunk 0
  xr = __builtin_nontemporal_load(reinterpret_cast<const fv4*>(xsrc));
#pragma unroll
  for (int j = 0; j < 4; ++j)
    br[j] = *reinterpret_cast<const uint4*>(bsrc + j * 8);
  {
    unsigned short* buf = lds[0];
    ushort4 hv;
    hv.x = f2bf(xr[0]); hv.y = f2bf(xr[1]); hv.z = f2bf(xr[2]); hv.w = f2bf(xr[3]);
    *reinterpret_cast<ushort4*>(&buf[10240 + xrow * 40 + xcol]) = hv;
#pragma unroll
    for (int j = 0; j < 4; ++j)
      *reinterpret_cast<uint4*>(&buf[tid * 40 + j * 8]) = br[j];
  }
  __syncthreads();
  for (int t = 0; t < 32; ++t) {
    unsigned short* buf  = lds[t & 1];
    unsigned short* nbuf = lds[(t & 1) ^ 1];
    if (t < 31) {      // issue next-chunk global loads BEFORE compute
      xr = __builtin_nontemporal_load(reinterpret_cast<const fv4*>(xsrc + (t + 1) * 32));
#pragma unroll
      for (int j = 0; j < 4; ++j)
        br[j] = *reinterpret_cast<const uint4*>(bsrc + (t + 1) * 32 + j * 8);
    }
    s8v a[4], b[2];
#pragma unroll
    for (int nq = 0; nq < 4; ++nq)
      a[nq] = *reinterpret_cast<const s8v*>(&buf[(w * 64 + nq * 16 + l15) * 40 + q8]);
#pragma unroll
    for (int mq = 0; mq < 2; ++mq)
      b[mq] = *reinterpret_cast<const s8v*>(&buf[10240 + (mq * 16 + l15) * 40 + q8]);
#pragma unroll
    for (int nq = 0; nq < 4; ++nq)
#pragma unroll
      for (int mq = 0; mq < 2; ++mq)
        acc[nq][mq] = __builtin_amdgcn_mfma_f32_16x16x32_bf16(a[nq], b[mq], acc[nq][mq], 0, 0, 0);
    if (t < 31) {      // write-late into the other buffer
      ushort4 hv;
      hv.x = f2bf(xr[0]); hv.y = f2bf(xr[1]); hv.z = f2bf(xr[2]); hv.w = f2bf(xr[3]);
      *reinterpret_cast<ushort4*>(&nbuf[10240 + xrow * 40 + xcol]) = hv;
#pragma unroll
      for (int j = 0; j < 4; ++j)
        *reinterpret_cast<uint4*>(&nbuf[tid * 40 + j * 8]) = br[j];
    }
    __syncthreads();
  }
#pragma unroll
  for (int nq = 0; nq < 4; ++nq) {
    int nb = w * 64 + nq * 16 + quad * 4;
#pragma unroll
    for (int mq = 0; mq < 2; ++mq) {
      int m = m0 + mq * 16 + l15;
      usv4 hv;
      hv[0] = f2bf(acc[nq][mq][0]); hv[1] = f2bf(acc[nq][mq][1]);
      hv[2] = f2bf(acc[nq][mq][2]); hv[3] = f2bf(acc[nq][mq][3]);
      __builtin_nontemporal_store(hv, reinterpret_cast<usv4*>(&u[m * 256 + nb]));
    }
  }
}

// ---------------------------------------------------------------------------
// phase 1: per-(b,subchunk) local scan, L=16, 64 blocks x 16 units.
// writes hs (bf16 local states) and subchunk finals into g0 rows (k+1)*8+b.
// block 0 also copies h0 into g0 rows 0..7.
__global__ __launch_bounds__(256, 1) void k_phase1(const unsigned short* __restrict__ u,
                                                   const unsigned short* __restrict__ Et,
                                                   unsigned short* __restrict__ hs,
                                                   float* __restrict__ g0,
                                                   const float* __restrict__ h0){
  __shared__ unsigned short hbuf[2][16][264];
  int tid = threadIdx.x, w = tid >> 6, lane = tid & 63;
  int l15 = lane & 15, quad = lane >> 4;
  int U0 = blockIdx.x * 16;
  s8v e[4][8];
#pragma unroll
  for (int ct = 0; ct < 4; ++ct) {
    int col = w * 64 + ct * 16 + l15;
#pragma unroll
    for (int kt = 0; kt < 8; ++kt)
      e[ct][kt] = *reinterpret_cast<const s8v*>(&Et[col * 256 + kt * 32 + quad * 8]);
  }
  int rowbase[4];
#pragma unroll
  for (int r = 0; r < 4; ++r) {
    int g = U0 + quad * 4 + r;
    rowbase[r] = ((g >> 7) * 2048 + (g & 127) * 16) * 256;
  }
  for (int i = tid; i < 16 * 264; i += 256) hbuf[0][0][i] = 0;
  if (blockIdx.x == 0)
    for (int i = tid; i < 2048; i += 256) g0[i] = h0[i];
  f4v acc[4] = {};
  float uv[4][4];
#pragma unroll
  for (int r = 0; r < 4; ++r)
#pragma unroll
    for (int ct = 0; ct < 4; ++ct)
      uv[r][ct] = bf2f(u[rowbase[r] + w * 64 + ct * 16 + l15]);
  __syncthreads();
  int cur = 0;
  for (int t = 0; t < 16; ++t) {
    s8v af[8];
#pragma unroll
    for (int kt = 0; kt < 8; ++kt)
      af[kt] = *reinterpret_cast<const s8v*>(&hbuf[cur][l15][kt * 32 + quad * 8]);
    float uvn[4][4];
    if (t < 15)
#pragma unroll
      for (int r = 0; r < 4; ++r)
#pragma unroll
        for (int ct = 0; ct < 4; ++ct)
          uvn[r][ct] = bf2f(u[rowbase[r] + (t + 1) * 256 + w * 64 + ct * 16 + l15]);
#pragma unroll
    for (int kt = 0; kt < 8; ++kt)
#pragma unroll
      for (int ct = 0; ct < 4; ++ct)
        acc[ct] = __builtin_amdgcn_mfma_f32_16x16x32_bf16(af[kt], e[ct][kt], acc[ct], 0, 0, 0);
    int nxt = cur ^ 1;
#pragma unroll
    for (int ct = 0; ct < 4; ++ct)
#pragma unroll
      for (int r = 0; r < 4; ++r) {
        acc[ct][r] += uv[r][ct];
        hbuf[nxt][quad * 4 + r][w * 64 + ct * 16 + l15] = f2bf(acc[ct][r]);
      }
    __syncthreads();
    int ul = w * 4 + quad, seg = l15;
    uint4 d0 = *reinterpret_cast<const uint4*>(&hbuf[nxt][ul][seg * 16]);
    uint4 d1 = *reinterpret_cast<const uint4*>(&hbuf[nxt][ul][seg * 16 + 8]);
    int g = U0 + ul;
    int hrow = ((g >> 7) * 2048 + (g & 127) * 16 + t) * 256;
    *reinterpret_cast<uint4*>(&hs[hrow + seg * 16]) = d0;
    *reinterpret_cast<uint4*>(&hs[hrow + seg * 16 + 8]) = d1;
    if (t < 15)
#pragma unroll
      for (int r = 0; r < 4; ++r)
#pragma unroll
        for (int ct = 0; ct < 4; ++ct)
          uv[r][ct] = uvn[r][ct];
    cur = nxt;
  }
#pragma unroll
  for (int ct = 0; ct < 4; ++ct)
#pragma unroll
    for (int r = 0; r < 4; ++r) {
      int g = U0 + quad * 4 + r;
      int k = g & 127, b = g >> 7;
      if (k < 127)
        g0[((k + 1) * 8 + b) * 256 + w * 64 + ct * 16 + l15] = acc[ct][r];
    }
}

// ---------------------------------------------------------------------------
// one Kogge-Stone round (separate launch per round):
// blocks 0..255:  go = gi + shift_rs(gi) @ cS : 32x32 tiles, 4 waves, each
//                 wave one 16x16 fragment, LDS-free.
// blocks 256..271: square cS into dh/dl for the next round (if dosq).
__global__ __launch_bounds__(256) void k_scanround(const float* __restrict__ gi,
    float* __restrict__ go,
    const unsigned short* __restrict__ cSh, const unsigned short* __restrict__ cSl,
    unsigned short* __restrict__ dh, unsigned short* __restrict__ dl,
    int rs, int dosq){
  __shared__ unsigned short Bh[64][40], Bl[64][40];
  int tid = threadIdx.x, lane = tid & 63, w = tid >> 6;
  int l15 = lane & 15, quad = lane >> 4, q8 = quad * 8;
  int bid = blockIdx.x;
  if (bid < 256) {
    int mt = bid >> 3, nt = bid & 7;
    int mbase = mt * 32 + (w >> 1) * 16;
    int nbase = nt * 32 + (w & 1) * 16;
    f4v acc;
#pragma unroll
    for (int r = 0; r < 4; ++r)
      acc[r] = gi[(mbase + quad * 4 + r) * 256 + nbase + l15];
    int ar = mbase + l15 - rs;
    const float* arow = gi + ar * 256;
    const unsigned short* bh_row = cSh + (nbase + l15) * 256;
    const unsigned short* bl_row = cSl + (nbase + l15) * 256;
    for (int kt = 0; kt < 256; kt += 32) {
      s8v ah, al;
      if (ar >= 0) split8(arow + kt + q8, ah, al);
      else { zero8(ah); zero8(al); }
      s8v bh = *reinterpret_cast<const s8v*>(bh_row + kt + q8);
      s8v bl = *reinterpret_cast<const s8v*>(bl_row + kt + q8);
      acc = __builtin_amdgcn_mfma_f32_16x16x32_bf16(ah, bh, acc, 0, 0, 0);
      acc = __builtin_amdgcn_mfma_f32_16x16x32_bf16(ah, bl, acc, 0, 0, 0);
      acc = __builtin_amdgcn_mfma_f32_16x16x32_bf16(al, bh, acc, 0, 0, 0);
    }
#pragma unroll
    for (int r = 0; r < 4; ++r)
      go[(mbase + quad * 4 + r) * 256 + nbase + l15] = acc[r];
  } else if (dosq) {
    // square the power: S' = S @ S
    int wr = w >> 1, wc = w & 1;
    int t = bid - 256;
    int m0 = (t >> 2) * 64, n0 = (t & 3) * 64;
    f4v acc[2][2] = {};
    for (int kt = 0; kt < 256; kt += 32) {
      __syncthreads();
      {
        int col = tid & 63, kk0 = (tid >> 6) * 8;
#pragma unroll
        for (int j = 0; j < 8; ++j) {
          int k = kt + kk0 + j;
          Bh[col][kk0 + j] = cSh[k * 256 + n0 + col];
          Bl[col][kk0 + j] = cSl[k * 256 + n0 + col];
        }
      }
      __syncthreads();
#pragma unroll
      for (int aq = 0; aq < 2; ++aq) {
        s8v ah = *reinterpret_cast<const s8v*>(&cSh[(m0 + wr * 32 + aq * 16 + l15) * 256 + kt + q8]);
        s8v al = *reinterpret_cast<const s8v*>(&cSl[(m0 + wr * 32 + aq * 16 + l15) * 256 + kt + q8]);
#pragma unroll
        for (int bq = 0; bq < 2; ++bq) {
          s8v bh = *reinterpret_cast<const s8v*>(&Bh[wc * 32 + bq * 16 + l15][q8]);
          s8v bl = *reinterpret_cast<const s8v*>(&Bl[wc * 32 + bq * 16 + l15][q8]);
          acc[aq][bq] = __builtin_amdgcn_mfma_f32_16x16x32_bf16(ah, bh, acc[aq][bq], 0, 0, 0);
          acc[aq][bq] = __builtin_amdgcn_mfma_f32_16x16x32_bf16(ah, bl, acc[aq][bq], 0, 0, 0);
          acc[aq][bq] = __builtin_amdgcn_mfma_f32_16x16x32_bf16(al, bh, acc[aq][bq], 0, 0, 0);
        }
      }
    }
#pragma unroll
    for (int aq = 0; aq < 2; ++aq)
#pragma unroll
      for (int bq = 0; bq < 2; ++bq)
#pragma unroll
        for (int r = 0; r < 4; ++r) {
          int gm = m0 + wr * 32 + aq * 16 + quad * 4 + r;
          int gn = n0 + wc * 32 + bq * 16 + l15;
          float v = acc[aq][bq][r];
          unsigned short hi = f2bf(v);
          dh[gm * 256 + gn] = hi;
          dl[gm * 256 + gn] = f2bf(v - bf2f(hi));
        }
  }
}

// ---------------------------------------------------------------------------
// carry expansion GEMM: hs[(b*2048 + k*16 + t)*256 + n] += carry[k*8+b] @ A_d^{t+1}
// SWAPPED operands, one 64x64 tile per block (grid 1024 -> 4 blocks/CU).
__global__ __launch_bounds__(256) void k_carryexp(const float* __restrict__ g,
    const unsigned short* __restrict__ QSh, const unsigned short* __restrict__ QSl,
    unsigned short* __restrict__ hs){
  int tid = threadIdx.x, lane = tid & 63, w = tid >> 6;
  int wm = w & 1, wn = w >> 1, l15 = lane & 15, quad = lane >> 4, q8 = quad * 8;
  int t = blockIdx.x;
  int mt = t >> 6, nt = t & 63;
  int m0 = mt * 64, n0 = nt * 64;
  f4v acc[2][2] = {};   // [nq][mq]
  for (int kt = 0; kt < 256; kt += 32) {
    s8v bh[2], bl[2];
#pragma unroll
    for (int mq = 0; mq < 2; ++mq)
      split8(&g[(m0 + wm * 32 + mq * 16 + l15) * 256 + kt + q8], bh[mq], bl[mq]);
#pragma unroll
    for (int nq = 0; nq < 2; ++nq) {
      int pc = n0 + wn * 32 + nq * 16 + l15;
      s8v ah = *reinterpret_cast<const s8v*>(&QSh[pc * 256 + kt + q8]);
      s8v al = *reinterpret_cast<const s8v*>(&QSl[pc * 256 + kt + q8]);
#pragma unroll
      for (int mq = 0; mq < 2; ++mq) {
        acc[nq][mq] = __builtin_amdgcn_mfma_f32_16x16x32_bf16(ah, bh[mq], acc[nq][mq], 0, 0, 0);
        acc[nq][mq] = __builtin_amdgcn_mfma_f32_16x16x32_bf16(ah, bl[mq], acc[nq][mq], 0, 0, 0);
        acc[nq][mq] = __builtin_amdgcn_mfma_f32_16x16x32_bf16(al, bh[mq], acc[nq][mq], 0, 0, 0);
      }
    }
  }
#pragma unroll
  for (int nq = 0; nq < 2; ++nq) {
    int gn = n0 + wn * 32 + nq * 16 + quad * 4;   // 4 consecutive pw cols
    int t0 = gn >> 8, nn = gn & 255;
#pragma unroll
    for (int mq = 0; mq < 2; ++mq) {
      int gm = m0 + wm * 32 + mq * 16 + l15;      // = k*8+b
      int k = gm >> 3, b = gm & 7;
      int idx = (b * 2048 + k * 16 + t0) * 256 + nn;
      ushort4 hv = *reinterpret_cast<const ushort4*>(&hs[idx]);
      ushort4 ov;
      ov.x = f2bf(bf2f(hv.x) + acc[nq][mq][0]);
      ov.y = f2bf(bf2f(hv.y) + acc[nq][mq][1]);
      ov.z = f2bf(bf2f(hv.z) + acc[nq][mq][2]);
      ov.w = f2bf(bf2f(hv.w) + acc[nq][mq][3]);
      *reinterpret_cast<ushort4*>(&hs[idx]) = ov;
    }
  }
}

// ---------------------------------------------------------------------------
// y = hs @ C + x*D : M=16384, K=256, N=1024. grid(128,8).
// SWAPPED operands, LDS-free. x loads + y stores NON-TEMPORAL (zero reuse
// streams must not evict Ct/hs from L2).
__global__ __launch_bounds__(256) void k_gemm_y(const unsigned short* __restrict__ hs,
                                                const unsigned short* __restrict__ Ct,
                                                const float* __restrict__ x,
                                                const float* __restrict__ D,
                                                float* __restrict__ y){
  int tid = threadIdx.x;
  int m0 = blockIdx.x * 128, n0 = blockIdx.y * 128;
  int w = tid >> 6, lane = tid & 63;
  int wm = w & 1, wn = w >> 1;
  int l15 = lane & 15, quad = lane >> 4, q8 = quad * 8;
  f4v acc[4][4] = {};   // [nq][mq]
  const unsigned short* cbase = Ct + (n0 + wn * 64 + l15) * 256;
  const unsigned short* hbase = hs + (size_t)(m0 + wm * 64 + l15) * 256;
  for (int kt = 0; kt < 256; kt += 32) {
    s8v a[4], b[4];
#pragma unroll
    for (int nq = 0; nq < 4; ++nq)
      a[nq] = *reinterpret_cast<const s8v*>(cbase + nq * 16 * 256 + kt + q8);
#pragma unroll
    for (int mq = 0; mq < 4; ++mq)
      b[mq] = *reinterpret_cast<const s8v*>(hbase + mq * 16 * 256 + kt + q8);
#pragma unroll
    for (int nq = 0; nq < 4; ++nq)
#pragma unroll
      for (int mq = 0; mq < 4; ++mq)
        acc[nq][mq] = __builtin_amdgcn_mfma_f32_16x16x32_bf16(a[nq], b[mq], acc[nq][mq], 0, 0, 0);
  }
#pragma unroll
  for (int nq = 0; nq < 4; ++nq) {
    int nb = n0 + wn * 64 + nq * 16 + quad * 4;
    float4 dv = *reinterpret_cast<const float4*>(&D[nb]);
#pragma unroll
    for (int mq = 0; mq < 4; ++mq) {
      int m = m0 + wm * 64 + mq * 16 + l15;
      fv4 xv = __builtin_nontemporal_load(
          reinterpret_cast<const fv4*>(&x[(size_t)m * 1024 + nb]));
      fv4 ov;
      ov[0] = acc[nq][mq][0] + xv[0] * dv.x;
      ov[1] = acc[nq][mq][1] + xv[1] * dv.y;
      ov[2] = acc[nq][mq][2] + xv[2] * dv.z;
      ov[3] = acc[nq][mq][3] + xv[3] * dv.w;
      __builtin_nontemporal_store(ov, reinterpret_cast<fv4*>(&y[(size_t)m * 1024 + nb]));
    }
  }
}

// ---------------------------------------------------------------------------
extern "C" void kernel_launch(void* const* d_in, const int* in_sizes, int n_in,
                              void* d_out, int out_size, void* d_ws, size_t ws_size,
                              hipStream_t stream) {
  (void)in_sizes; (void)n_in; (void)out_size; (void)ws_size;
  const float* x  = (const float*)d_in[0];
  const float* A  = (const float*)d_in[1];
  const float* B  = (const float*)d_in[2];
  const float* C  = (const float*)d_in[3];
  const float* D  = (const float*)d_in[4];
  const float* h0 = (const float*)d_in[5];
  float* y = (float*)d_out;

  char* ws = (char*)d_ws;
  size_t off = 0;
  auto alloc = [&](size_t bytes) { void* p = ws + off; off += (bytes + 255) & ~(size_t)255; return p; };
  float* Mt  = (float*)alloc(262144);
  float* Tp0 = (float*)alloc(262144);
  float* Tp1 = (float*)alloc(262144);
  unsigned short* QSh = (unsigned short*)alloc(2097152);  // 16 x 256x256 hi
  unsigned short* QSl = (unsigned short*)alloc(2097152);  // 16 x 256x256 lo
  unsigned short* Et  = (unsigned short*)alloc(131072);
  unsigned short* Sh0 = (unsigned short*)alloc(131072);
  unsigned short* Sl0 = (unsigned short*)alloc(131072);
  unsigned short* Sh1 = (unsigned short*)alloc(131072);
  unsigned short* Sl1 = (unsigned short*)alloc(131072);
  float* g0 = (float*)alloc(1048576);
  float* g1 = (float*)alloc(1048576);
  unsigned short* Bt = (unsigned short*)alloc(524288);
  unsigned short* Ct = (unsigned short*)alloc(524288);
  unsigned short* u  = (unsigned short*)alloc(8388608);
  unsigned short* hs = (unsigned short*)alloc(8388608);

  k_prep<<<2304, 256, 0, stream>>>(A, B, C, Mt, Tp0, Bt, Ct);

  // expm Taylor-4 (Horner), 3 dependent GEMM phases -> kernel boundaries
  k_taylor<<<16, 256, 0, stream>>>(Mt, Tp0, Tp1, QSh, QSl, Et, 1.0f / 3.0f, 0);
  k_taylor<<<16, 256, 0, stream>>>(Mt, Tp1, Tp0, QSh, QSl, Et, 0.5f, 0);
  k_taylor<<<16, 256, 0, stream>>>(Mt, Tp0, Tp1, QSh, QSl, Et, 1.0f, 1);

  // power stack via log-doubling: QS[d+j] = QS[j] @ QS[d-1]
  for (int d = 1; d <= 8; d <<= 1)
    k_power<<<d * 16, 256, 0, stream>>>(QSh, QSl, d);

  k_gemm_u<<<512, 256, 0, stream>>>(x, Bt, u);
  k_phase1<<<64, 256, 0, stream>>>(u, Et, hs, g0, h0);

  // Kogge-Stone scan over carries: 7 rounds, ping-pong host-side
  {
    const unsigned short* cSh = QSh + 15 * 65536;   // A16^T = QS[15]
    const unsigned short* cSl = QSl + 15 * 65536;
    float* gi = g0;
    float* go = g1;
    for (int rd = 0; rd < 7; ++rd) {
      int rs = 8 << rd;
      int dosq = (rd < 6) ? 1 : 0;
      unsigned short* dh = (rd & 1) ? Sh1 : Sh0;
      unsigned short* dl = (rd & 1) ? Sl1 : Sl0;
      k_scanround<<<dosq ? 272 : 256, 256, 0, stream>>>(gi, go, cSh, cSl, dh, dl, rs, dosq);
      if (dosq) {
        cSh = dh; cSl = dl;
        float* tg = gi; gi = go; go = tg;
      }
    }
  }

  k_carryexp<<<1024, 256, 0, stream>>>(g1, QSh, QSl, hs);
  k_gemm_y<<<dim3(128, 8), 256, 0, stream>>>(hs, Ct, x, D, y);
}

// Round 11
// 401.774 us; speedup vs baseline: 1.1498x; 1.1498x over previous
//
#include <hip/hip_runtime.h>

typedef float f4v __attribute__((ext_vector_type(4)));
typedef short s8v __attribute__((ext_vector_type(8)));

__device__ __forceinline__ unsigned short f2bf(float x){
  union { float f; unsigned u; } v; v.f = x;
  unsigned r = v.u + 0x7fffu + ((v.u >> 16) & 1u);
  return (unsigned short)(r >> 16);
}
__device__ __forceinline__ float bf2f(unsigned short b){
  union { unsigned u; float f; } v; v.u = ((unsigned)b) << 16;
  return v.f;
}
// split 8 consecutive f32 into hi/lo bf16 fragments
__device__ __forceinline__ void split8(const float* __restrict__ p, s8v& h, s8v& l){
  float4 v0 = *reinterpret_cast<const float4*>(p);
  float4 v1 = *reinterpret_cast<const float4*>(p + 4);
  float a[8] = {v0.x, v0.y, v0.z, v0.w, v1.x, v1.y, v1.z, v1.w};
#pragma unroll
  for (int j = 0; j < 8; ++j) {
    unsigned short hi = f2bf(a[j]);
    h[j] = (short)hi;
    l[j] = (short)f2bf(a[j] - bf2f(hi));
  }
}
__device__ __forceinline__ void zero8(s8v& v){
#pragma unroll
  for (int j = 0; j < 8; ++j) v[j] = 0;
}

// ---------------------------------------------------------------------------
// prep: Mt = 0.1*A^T ; Tp0 = I + Mt/4 (Taylor-4 innermost) ;
//       Btc[k/32][n][k%32] = B[k][n] bf16 (CHUNK-MAJOR: each K-chunk of the
//       full B operand is one contiguous 16 KB block) ; Ct[j][n]=C[n][j] bf16
__global__ void k_prep(const float* __restrict__ A, const float* __restrict__ B,
                       const float* __restrict__ C,
                       float* __restrict__ Mt, float* __restrict__ Tp0,
                       unsigned short* __restrict__ Btc, unsigned short* __restrict__ Ct){
  int i = blockIdx.x * 256 + threadIdx.x;
  const int tot = 65536 + 262144 + 262144;
  for (; i < tot; i += gridDim.x * 256) {
    if (i < 65536) {
      int r = i >> 8, c = i & 255;
      float m = 0.1f * A[c * 256 + r];
      Mt[i] = m;
      Tp0[i] = m * 0.25f + (r == c ? 1.0f : 0.0f);
    } else if (i < 65536 + 262144) {
      int j = i - 65536;            // n*1024 + k
      int n = j >> 10, k = j & 1023;
      Btc[(k >> 5) * 8192 + n * 32 + (k & 31)] = f2bf(B[k * 256 + n]);
    } else {
      int j = i - 65536 - 262144;   // col*256 + n
      int col = j >> 8, n = j & 255;
      Ct[j] = f2bf(C[n * 1024 + col]);
    }
  }
}

// ---------------------------------------------------------------------------
// Taylor phase (one of 3): out = alpha*(Mt @ Bsrc) + I. grid = 16 blocks.
// final phase writes QS[0] (hi/lo bf16) and Et = Q1 - I instead of f32 out.
__global__ __launch_bounds__(256) void k_taylor(const float* __restrict__ Mt,
    const float* __restrict__ Bsrc, float* __restrict__ Odst,
    unsigned short* __restrict__ QSh, unsigned short* __restrict__ QSl,
    unsigned short* __restrict__ Et, float alpha, int fin){
  __shared__ unsigned short Bh[64][40], Bl[64][40];
  int tid = threadIdx.x, lane = tid & 63, w = tid >> 6;
  int wr = w >> 1, wc = w & 1, l15 = lane & 15, quad = lane >> 4, q8 = quad * 8;
  int bid = blockIdx.x;
  int m0 = (bid >> 2) * 64, n0 = (bid & 3) * 64;
  f4v acc[2][2] = {};
  for (int kt = 0; kt < 256; kt += 32) {
    __syncthreads();
    {
      int col = tid & 63, kk0 = (tid >> 6) * 8;
#pragma unroll
      for (int j = 0; j < 8; ++j) {
        float v = Bsrc[(kt + kk0 + j) * 256 + n0 + col];
        unsigned short hi = f2bf(v);
        Bh[col][kk0 + j] = hi;
        Bl[col][kk0 + j] = f2bf(v - bf2f(hi));
      }
    }
    __syncthreads();
#pragma unroll
    for (int aq = 0; aq < 2; ++aq) {
      s8v ah, al;
      split8(&Mt[(m0 + wr * 32 + aq * 16 + l15) * 256 + kt + q8], ah, al);
#pragma unroll
      for (int bq = 0; bq < 2; ++bq) {
        s8v bh = *reinterpret_cast<const s8v*>(&Bh[wc * 32 + bq * 16 + l15][q8]);
        s8v bl = *reinterpret_cast<const s8v*>(&Bl[wc * 32 + bq * 16 + l15][q8]);
        acc[aq][bq] = __builtin_amdgcn_mfma_f32_16x16x32_bf16(ah, bh, acc[aq][bq], 0, 0, 0);
        acc[aq][bq] = __builtin_amdgcn_mfma_f32_16x16x32_bf16(ah, bl, acc[aq][bq], 0, 0, 0);
        acc[aq][bq] = __builtin_amdgcn_mfma_f32_16x16x32_bf16(al, bh, acc[aq][bq], 0, 0, 0);
      }
    }
  }
#pragma unroll
  for (int aq = 0; aq < 2; ++aq)
#pragma unroll
    for (int bq = 0; bq < 2; ++bq)
#pragma unroll
      for (int r = 0; r < 4; ++r) {
        int gm = m0 + wr * 32 + aq * 16 + quad * 4 + r;
        int gn = n0 + wc * 32 + bq * 16 + l15;
        float raw = alpha * acc[aq][bq][r];
        float v = raw + (gm == gn ? 1.0f : 0.0f);
        if (!fin) {
          Odst[gm * 256 + gn] = v;
        } else {
          unsigned short hi = f2bf(v);
          QSh[gm * 256 + gn] = hi;
          QSl[gm * 256 + gn] = f2bf(v - bf2f(hi));
          Et[gm * 256 + gn] = f2bf(raw);   // Q1 - I
        }
      }
}

// ---------------------------------------------------------------------------
// power-stack doubling phase (one of 4 launches, d in {1,2,4,8}):
// QS[d+j] = QS[j] @ QS[d-1], j<d. grid = d*16 blocks. All tiles independent.
__global__ __launch_bounds__(256) void k_power(unsigned short* __restrict__ QSh,
    unsigned short* __restrict__ QSl, int d){
  __shared__ unsigned short Bh[64][40], Bl[64][40];
  int tid = threadIdx.x, lane = tid & 63, w = tid >> 6;
  int wr = w >> 1, wc = w & 1, l15 = lane & 15, quad = lane >> 4, q8 = quad * 8;
  int bid = blockIdx.x;
  int mt = bid >> 2, nt = bid & 3;
  int m0 = mt * 64, n0 = nt * 64;
  int bro = (d - 1) * 256;
  f4v acc[2][2] = {};
  for (int kt = 0; kt < 256; kt += 32) {
    __syncthreads();
    {
      int col = tid & 63, kk0 = (tid >> 6) * 8;
#pragma unroll
      for (int j = 0; j < 8; ++j) {
        int k = kt + kk0 + j;
        Bh[col][kk0 + j] = QSh[(bro + k) * 256 + n0 + col];
        Bl[col][kk0 + j] = QSl[(bro + k) * 256 + n0 + col];
      }
    }
    __syncthreads();
#pragma unroll
    for (int aq = 0; aq < 2; ++aq) {
      s8v ah = *reinterpret_cast<const s8v*>(&QSh[(m0 + wr * 32 + aq * 16 + l15) * 256 + kt + q8]);
      s8v al = *reinterpret_cast<const s8v*>(&QSl[(m0 + wr * 32 + aq * 16 + l15) * 256 + kt + q8]);
#pragma unroll
      for (int bq = 0; bq < 2; ++bq) {
        s8v bh = *reinterpret_cast<const s8v*>(&Bh[wc * 32 + bq * 16 + l15][q8]);
        s8v bl = *reinterpret_cast<const s8v*>(&Bl[wc * 32 + bq * 16 + l15][q8]);
        acc[aq][bq] = __builtin_amdgcn_mfma_f32_16x16x32_bf16(ah, bh, acc[aq][bq], 0, 0, 0);
        acc[aq][bq] = __builtin_amdgcn_mfma_f32_16x16x32_bf16(ah, bl, acc[aq][bq], 0, 0, 0);
        acc[aq][bq] = __builtin_amdgcn_mfma_f32_16x16x32_bf16(al, bh, acc[aq][bq], 0, 0, 0);
      }
    }
  }
#pragma unroll
  for (int aq = 0; aq < 2; ++aq)
#pragma unroll
    for (int bq = 0; bq < 2; ++bq)
#pragma unroll
      for (int r = 0; r < 4; ++r) {
        int gm = m0 + wr * 32 + aq * 16 + quad * 4 + r;
        int gn = n0 + wc * 32 + bq * 16 + l15;
        float v = acc[aq][bq][r];
        unsigned short hi = f2bf(v);
        QSh[(d * 256 + gm) * 256 + gn] = hi;
        QSl[(d * 256 + gm) * 256 + gn] = f2bf(v - bf2f(hi));
      }
}

// ---------------------------------------------------------------------------
// u_bf16 = bf16(x @ B) : M=16384, K=1024, N=256. grid = 512 blocks.
// Block = 32 m x 256 n, LDS double-buffered. Btc is CHUNK-MAJOR so each
// K-chunk staging instruction is 1 KB unit-stride per wave (no 64B scatter).
// Next-chunk loads issued before MFMAs; write-late into other buffer.
__global__ __launch_bounds__(256) void k_gemm_u(const float* __restrict__ x,
                                                const unsigned short* __restrict__ Btc,
                                                unsigned short* __restrict__ u){
  // per buffer: Btile 256 rows x stride 40 shorts (offset 0),
  //             Atile 32 rows x stride 40 shorts (offset 10240)
  __shared__ unsigned short lds[2][256 * 40 + 32 * 40];
  int tid = threadIdx.x;
  int m0 = blockIdx.x * 32;
  int w = tid >> 6, lane = tid & 63;
  int l15 = lane & 15, quad = lane >> 4, q8 = quad * 8;
  // x staging: 32 rows x 8 thr/row, 16B each (128B contiguous per row)
  int xrow = tid >> 3, xcol = (tid & 7) * 4;
  const float* xsrc = x + (size_t)(m0 + xrow) * 1024 + xcol;
  // Btc staging: instr j reads chunk bytes [j*4096 + tid*16) -> fully coalesced.
  // thread tid, instr j holds row n = j*64 + (tid>>2), kk = (tid&3)*8 .. +8
  const unsigned short* bsrc = Btc + tid * 8;
  int brow[4], bcol = (tid & 3) * 8;
#pragma unroll
  for (int j = 0; j < 4; ++j) brow[j] = j * 64 + (tid >> 2);
  f4v acc[4][2] = {};   // [nq][mq]
  float4 xr;
  uint4 br[4];
  // prologue: stage chunk 0
  xr = *reinterpret_cast<const float4*>(xsrc);
#pragma unroll
  for (int j = 0; j < 4; ++j)
    br[j] = *reinterpret_cast<const uint4*>(bsrc + j * 2048);
  {
    unsigned short* buf = lds[0];
    ushort4 hv;
    hv.x = f2bf(xr.x); hv.y = f2bf(xr.y); hv.z = f2bf(xr.z); hv.w = f2bf(xr.w);
    *reinterpret_cast<ushort4*>(&buf[10240 + xrow * 40 + xcol]) = hv;
#pragma unroll
    for (int j = 0; j < 4; ++j)
      *reinterpret_cast<uint4*>(&buf[brow[j] * 40 + bcol]) = br[j];
  }
  __syncthreads();
  for (int t = 0; t < 32; ++t) {
    unsigned short* buf  = lds[t & 1];
    unsigned short* nbuf = lds[(t & 1) ^ 1];
    if (t < 31) {      // issue next-chunk global loads BEFORE compute
      xr = *reinterpret_cast<const float4*>(xsrc + (t + 1) * 32);
#pragma unroll
      for (int j = 0; j < 4; ++j)
        br[j] = *reinterpret_cast<const uint4*>(bsrc + (t + 1) * 8192 + j * 2048);
    }
    s8v a[4], b[2];
#pragma unroll
    for (int nq = 0; nq < 4; ++nq)
      a[nq] = *reinterpret_cast<const s8v*>(&buf[(w * 64 + nq * 16 + l15) * 40 + q8]);
#pragma unroll
    for (int mq = 0; mq < 2; ++mq)
      b[mq] = *reinterpret_cast<const s8v*>(&buf[10240 + (mq * 16 + l15) * 40 + q8]);
#pragma unroll
    for (int nq = 0; nq < 4; ++nq)
#pragma unroll
      for (int mq = 0; mq < 2; ++mq)
        acc[nq][mq] = __builtin_amdgcn_mfma_f32_16x16x32_bf16(a[nq], b[mq], acc[nq][mq], 0, 0, 0);
    if (t < 31) {      // write-late into the other buffer
      ushort4 hv;
      hv.x = f2bf(xr.x); hv.y = f2bf(xr.y); hv.z = f2bf(xr.z); hv.w = f2bf(xr.w);
      *reinterpret_cast<ushort4*>(&nbuf[10240 + xrow * 40 + xcol]) = hv;
#pragma unroll
      for (int j = 0; j < 4; ++j)
        *reinterpret_cast<uint4*>(&nbuf[brow[j] * 40 + bcol]) = br[j];
    }
    __syncthreads();
  }
#pragma unroll
  for (int nq = 0; nq < 4; ++nq) {
    int nb = w * 64 + nq * 16 + quad * 4;
#pragma unroll
    for (int mq = 0; mq < 2; ++mq) {
      int m = m0 + mq * 16 + l15;
      ushort4 hv;
      hv.x = f2bf(acc[nq][mq][0]); hv.y = f2bf(acc[nq][mq][1]);
      hv.z = f2bf(acc[nq][mq][2]); hv.w = f2bf(acc[nq][mq][3]);
      *reinterpret_cast<ushort4*>(&u[m * 256 + nb]) = hv;
    }
  }
}

// ---------------------------------------------------------------------------
// phase 1: per-(b,subchunk) local scan, L=16, 64 blocks x 16 units.
// writes hs (bf16 local states) and subchunk finals into g0 rows (k+1)*8+b.
// block 0 also copies h0 into g0 rows 0..7.
__global__ __launch_bounds__(256, 1) void k_phase1(const unsigned short* __restrict__ u,
                                                   const unsigned short* __restrict__ Et,
                                                   unsigned short* __restrict__ hs,
                                                   float* __restrict__ g0,
                                                   const float* __restrict__ h0){
  __shared__ unsigned short hbuf[2][16][264];
  int tid = threadIdx.x, w = tid >> 6, lane = tid & 63;
  int l15 = lane & 15, quad = lane >> 4;
  int U0 = blockIdx.x * 16;
  s8v e[4][8];
#pragma unroll
  for (int ct = 0; ct < 4; ++ct) {
    int col = w * 64 + ct * 16 + l15;
#pragma unroll
    for (int kt = 0; kt < 8; ++kt)
      e[ct][kt] = *reinterpret_cast<const s8v*>(&Et[col * 256 + kt * 32 + quad * 8]);
  }
  int rowbase[4];
#pragma unroll
  for (int r = 0; r < 4; ++r) {
    int g = U0 + quad * 4 + r;
    rowbase[r] = ((g >> 7) * 2048 + (g & 127) * 16) * 256;
  }
  for (int i = tid; i < 16 * 264; i += 256) hbuf[0][0][i] = 0;
  if (blockIdx.x == 0)
    for (int i = tid; i < 2048; i += 256) g0[i] = h0[i];
  f4v acc[4] = {};
  float uv[4][4];
#pragma unroll
  for (int r = 0; r < 4; ++r)
#pragma unroll
    for (int ct = 0; ct < 4; ++ct)
      uv[r][ct] = bf2f(u[rowbase[r] + w * 64 + ct * 16 + l15]);
  __syncthreads();
  int cur = 0;
  for (int t = 0; t < 16; ++t) {
    s8v af[8];
#pragma unroll
    for (int kt = 0; kt < 8; ++kt)
      af[kt] = *reinterpret_cast<const s8v*>(&hbuf[cur][l15][kt * 32 + quad * 8]);
    float uvn[4][4];
    if (t < 15)
#pragma unroll
      for (int r = 0; r < 4; ++r)
#pragma unroll
        for (int ct = 0; ct < 4; ++ct)
          uvn[r][ct] = bf2f(u[rowbase[r] + (t + 1) * 256 + w * 64 + ct * 16 + l15]);
#pragma unroll
    for (int kt = 0; kt < 8; ++kt)
#pragma unroll
      for (int ct = 0; ct < 4; ++ct)
        acc[ct] = __builtin_amdgcn_mfma_f32_16x16x32_bf16(af[kt], e[ct][kt], acc[ct], 0, 0, 0);
    int nxt = cur ^ 1;
#pragma unroll
    for (int ct = 0; ct < 4; ++ct)
#pragma unroll
      for (int r = 0; r < 4; ++r) {
        acc[ct][r] += uv[r][ct];
        hbuf[nxt][quad * 4 + r][w * 64 + ct * 16 + l15] = f2bf(acc[ct][r]);
      }
    __syncthreads();
    int ul = w * 4 + quad, seg = l15;
    uint4 d0 = *reinterpret_cast<const uint4*>(&hbuf[nxt][ul][seg * 16]);
    uint4 d1 = *reinterpret_cast<const uint4*>(&hbuf[nxt][ul][seg * 16 + 8]);
    int g = U0 + ul;
    int hrow = ((g >> 7) * 2048 + (g & 127) * 16 + t) * 256;
    *reinterpret_cast<uint4*>(&hs[hrow + seg * 16]) = d0;
    *reinterpret_cast<uint4*>(&hs[hrow + seg * 16 + 8]) = d1;
    if (t < 15)
#pragma unroll
      for (int r = 0; r < 4; ++r)
#pragma unroll
        for (int ct = 0; ct < 4; ++ct)
          uv[r][ct] = uvn[r][ct];
    cur = nxt;
  }
#pragma unroll
  for (int ct = 0; ct < 4; ++ct)
#pragma unroll
    for (int r = 0; r < 4; ++r) {
      int g = U0 + quad * 4 + r;
      int k = g & 127, b = g >> 7;
      if (k < 127)
        g0[((k + 1) * 8 + b) * 256 + w * 64 + ct * 16 + l15] = acc[ct][r];
    }
}

// ---------------------------------------------------------------------------
// one Kogge-Stone round (separate launch per round):
// blocks 0..255:  go = gi + shift_rs(gi) @ cS : 32x32 tiles, 4 waves, each
//                 wave one 16x16 fragment, LDS-free.
// blocks 256..271: square cS into dh/dl for the next round (if dosq).
__global__ __launch_bounds__(256) void k_scanround(const float* __restrict__ gi,
    float* __restrict__ go,
    const unsigned short* __restrict__ cSh, const unsigned short* __restrict__ cSl,
    unsigned short* __restrict__ dh, unsigned short* __restrict__ dl,
    int rs, int dosq){
  __shared__ unsigned short Bh[64][40], Bl[64][40];
  int tid = threadIdx.x, lane = tid & 63, w = tid >> 6;
  int l15 = lane & 15, quad = lane >> 4, q8 = quad * 8;
  int bid = blockIdx.x;
  if (bid < 256) {
    int mt = bid >> 3, nt = bid & 7;
    int mbase = mt * 32 + (w >> 1) * 16;
    int nbase = nt * 32 + (w & 1) * 16;
    f4v acc;
#pragma unroll
    for (int r = 0; r < 4; ++r)
      acc[r] = gi[(mbase + quad * 4 + r) * 256 + nbase + l15];
    int ar = mbase + l15 - rs;
    const float* arow = gi + ar * 256;
    const unsigned short* bh_row = cSh + (nbase + l15) * 256;
    const unsigned short* bl_row = cSl + (nbase + l15) * 256;
    for (int kt = 0; kt < 256; kt += 32) {
      s8v ah, al;
      if (ar >= 0) split8(arow + kt + q8, ah, al);
      else { zero8(ah); zero8(al); }
      s8v bh = *reinterpret_cast<const s8v*>(bh_row + kt + q8);
      s8v bl = *reinterpret_cast<const s8v*>(bl_row + kt + q8);
      acc = __builtin_amdgcn_mfma_f32_16x16x32_bf16(ah, bh, acc, 0, 0, 0);
      acc = __builtin_amdgcn_mfma_f32_16x16x32_bf16(ah, bl, acc, 0, 0, 0);
      acc = __builtin_amdgcn_mfma_f32_16x16x32_bf16(al, bh, acc, 0, 0, 0);
    }
#pragma unroll
    for (int r = 0; r < 4; ++r)
      go[(mbase + quad * 4 + r) * 256 + nbase + l15] = acc[r];
  } else if (dosq) {
    // square the power: S' = S @ S
    int wr = w >> 1, wc = w & 1;
    int t = bid - 256;
    int m0 = (t >> 2) * 64, n0 = (t & 3) * 64;
    f4v acc[2][2] = {};
    for (int kt = 0; kt < 256; kt += 32) {
      __syncthreads();
      {
        int col = tid & 63, kk0 = (tid >> 6) * 8;
#pragma unroll
        for (int j = 0; j < 8; ++j) {
          int k = kt + kk0 + j;
          Bh[col][kk0 + j] = cSh[k * 256 + n0 + col];
          Bl[col][kk0 + j] = cSl[k * 256 + n0 + col];
        }
      }
      __syncthreads();
#pragma unroll
      for (int aq = 0; aq < 2; ++aq) {
        s8v ah = *reinterpret_cast<const s8v*>(&cSh[(m0 + wr * 32 + aq * 16 + l15) * 256 + kt + q8]);
        s8v al = *reinterpret_cast<const s8v*>(&cSl[(m0 + wr * 32 + aq * 16 + l15) * 256 + kt + q8]);
#pragma unroll
        for (int bq = 0; bq < 2; ++bq) {
          s8v bh = *reinterpret_cast<const s8v*>(&Bh[wc * 32 + bq * 16 + l15][q8]);
          s8v bl = *reinterpret_cast<const s8v*>(&Bl[wc * 32 + bq * 16 + l15][q8]);
          acc[aq][bq] = __builtin_amdgcn_mfma_f32_16x16x32_bf16(ah, bh, acc[aq][bq], 0, 0, 0);
          acc[aq][bq] = __builtin_amdgcn_mfma_f32_16x16x32_bf16(ah, bl, acc[aq][bq], 0, 0, 0);
          acc[aq][bq] = __builtin_amdgcn_mfma_f32_16x16x32_bf16(al, bh, acc[aq][bq], 0, 0, 0);
        }
      }
    }
#pragma unroll
    for (int aq = 0; aq < 2; ++aq)
#pragma unroll
      for (int bq = 0; bq < 2; ++bq)
#pragma unroll
        for (int r = 0; r < 4; ++r) {
          int gm = m0 + wr * 32 + aq * 16 + quad * 4 + r;
          int gn = n0 + wc * 32 + bq * 16 + l15;
          float v = acc[aq][bq][r];
          unsigned short hi = f2bf(v);
          dh[gm * 256 + gn] = hi;
          dl[gm * 256 + gn] = f2bf(v - bf2f(hi));
        }
  }
}

// ---------------------------------------------------------------------------
// carry expansion GEMM: hs[(b*2048 + k*16 + t)*256 + n] += carry[k*8+b] @ A_d^{t+1}
// SWAPPED operands, one 64x64 tile per block (grid 1024 -> 4 blocks/CU).
__global__ __launch_bounds__(256) void k_carryexp(const float* __restrict__ g,
    const unsigned short* __restrict__ QSh, const unsigned short* __restrict__ QSl,
    unsigned short* __restrict__ hs){
  int tid = threadIdx.x, lane = tid & 63, w = tid >> 6;
  int wm = w & 1, wn = w >> 1, l15 = lane & 15, quad = lane >> 4, q8 = quad * 8;
  int t = blockIdx.x;
  int mt = t >> 6, nt = t & 63;
  int m0 = mt * 64, n0 = nt * 64;
  f4v acc[2][2] = {};   // [nq][mq]
  for (int kt = 0; kt < 256; kt += 32) {
    s8v bh[2], bl[2];
#pragma unroll
    for (int mq = 0; mq < 2; ++mq)
      split8(&g[(m0 + wm * 32 + mq * 16 + l15) * 256 + kt + q8], bh[mq], bl[mq]);
#pragma unroll
    for (int nq = 0; nq < 2; ++nq) {
      int pc = n0 + wn * 32 + nq * 16 + l15;
      s8v ah = *reinterpret_cast<const s8v*>(&QSh[pc * 256 + kt + q8]);
      s8v al = *reinterpret_cast<const s8v*>(&QSl[pc * 256 + kt + q8]);
#pragma unroll
      for (int mq = 0; mq < 2; ++mq) {
        acc[nq][mq] = __builtin_amdgcn_mfma_f32_16x16x32_bf16(ah, bh[mq], acc[nq][mq], 0, 0, 0);
        acc[nq][mq] = __builtin_amdgcn_mfma_f32_16x16x32_bf16(ah, bl[mq], acc[nq][mq], 0, 0, 0);
        acc[nq][mq] = __builtin_amdgcn_mfma_f32_16x16x32_bf16(al, bh[mq], acc[nq][mq], 0, 0, 0);
      }
    }
  }
#pragma unroll
  for (int nq = 0; nq < 2; ++nq) {
    int gn = n0 + wn * 32 + nq * 16 + quad * 4;   // 4 consecutive pw cols
    int t0 = gn >> 8, nn = gn & 255;
#pragma unroll
    for (int mq = 0; mq < 2; ++mq) {
      int gm = m0 + wm * 32 + mq * 16 + l15;      // = k*8+b
      int k = gm >> 3, b = gm & 7;
      int idx = (b * 2048 + k * 16 + t0) * 256 + nn;
      ushort4 hv = *reinterpret_cast<const ushort4*>(&hs[idx]);
      ushort4 ov;
      ov.x = f2bf(bf2f(hv.x) + acc[nq][mq][0]);
      ov.y = f2bf(bf2f(hv.y) + acc[nq][mq][1]);
      ov.z = f2bf(bf2f(hv.z) + acc[nq][mq][2]);
      ov.w = f2bf(bf2f(hv.w) + acc[nq][mq][3]);
      *reinterpret_cast<ushort4*>(&hs[idx]) = ov;
    }
  }
}

// ---------------------------------------------------------------------------
// y = hs @ C + x*D : M=16384, K=256, N=1024. grid(128,8).
// SWAPPED operands, LDS-free, cached loads (x is L3-resident — NT reverted).
__global__ __launch_bounds__(256) void k_gemm_y(const unsigned short* __restrict__ hs,
                                                const unsigned short* __restrict__ Ct,
                                                const float* __restrict__ x,
                                                const float* __restrict__ D,
                                                float* __restrict__ y){
  int tid = threadIdx.x;
  int m0 = blockIdx.x * 128, n0 = blockIdx.y * 128;
  int w = tid >> 6, lane = tid & 63;
  int wm = w & 1, wn = w >> 1;
  int l15 = lane & 15, quad = lane >> 4, q8 = quad * 8;
  f4v acc[4][4] = {};   // [nq][mq]
  const unsigned short* cbase = Ct + (n0 + wn * 64 + l15) * 256;
  const unsigned short* hbase = hs + (size_t)(m0 + wm * 64 + l15) * 256;
  for (int kt = 0; kt < 256; kt += 32) {
    s8v a[4], b[4];
#pragma unroll
    for (int nq = 0; nq < 4; ++nq)
      a[nq] = *reinterpret_cast<const s8v*>(cbase + nq * 16 * 256 + kt + q8);
#pragma unroll
    for (int mq = 0; mq < 4; ++mq)
      b[mq] = *reinterpret_cast<const s8v*>(hbase + mq * 16 * 256 + kt + q8);
#pragma unroll
    for (int nq = 0; nq < 4; ++nq)
#pragma unroll
      for (int mq = 0; mq < 4; ++mq)
        acc[nq][mq] = __builtin_amdgcn_mfma_f32_16x16x32_bf16(a[nq], b[mq], acc[nq][mq], 0, 0, 0);
  }
#pragma unroll
  for (int nq = 0; nq < 4; ++nq) {
    int nb = n0 + wn * 64 + nq * 16 + quad * 4;
    float4 dv = *reinterpret_cast<const float4*>(&D[nb]);
#pragma unroll
    for (int mq = 0; mq < 4; ++mq) {
      int m = m0 + wm * 64 + mq * 16 + l15;
      float4 xv = *reinterpret_cast<const float4*>(&x[(size_t)m * 1024 + nb]);
      float4 ov;
      ov.x = acc[nq][mq][0] + xv.x * dv.x;
      ov.y = acc[nq][mq][1] + xv.y * dv.y;
      ov.z = acc[nq][mq][2] + xv.z * dv.z;
      ov.w = acc[nq][mq][3] + xv.w * dv.w;
      *reinterpret_cast<float4*>(&y[(size_t)m * 1024 + nb]) = ov;
    }
  }
}

// ---------------------------------------------------------------------------
extern "C" void kernel_launch(void* const* d_in, const int* in_sizes, int n_in,
                              void* d_out, int out_size, void* d_ws, size_t ws_size,
                              hipStream_t stream) {
  (void)in_sizes; (void)n_in; (void)out_size; (void)ws_size;
  const float* x  = (const float*)d_in[0];
  const float* A  = (const float*)d_in[1];
  const float* B  = (const float*)d_in[2];
  const float* C  = (const float*)d_in[3];
  const float* D  = (const float*)d_in[4];
  const float* h0 = (const float*)d_in[5];
  float* y = (float*)d_out;

  char* ws = (char*)d_ws;
  size_t off = 0;
  auto alloc = [&](size_t bytes) { void* p = ws + off; off += (bytes + 255) & ~(size_t)255; return p; };
  float* Mt  = (float*)alloc(262144);
  float* Tp0 = (float*)alloc(262144);
  float* Tp1 = (float*)alloc(262144);
  unsigned short* QSh = (unsigned short*)alloc(2097152);  // 16 x 256x256 hi
  unsigned short* QSl = (unsigned short*)alloc(2097152);  // 16 x 256x256 lo
  unsigned short* Et  = (unsigned short*)alloc(131072);
  unsigned short* Sh0 = (unsigned short*)alloc(131072);
  unsigned short* Sl0 = (unsigned short*)alloc(131072);
  unsigned short* Sh1 = (unsigned short*)alloc(131072);
  unsigned short* Sl1 = (unsigned short*)alloc(131072);
  float* g0 = (float*)alloc(1048576);
  float* g1 = (float*)alloc(1048576);
  unsigned short* Btc = (unsigned short*)alloc(524288);
  unsigned short* Ct = (unsigned short*)alloc(524288);
  unsigned short* u  = (unsigned short*)alloc(8388608);
  unsigned short* hs = (unsigned short*)alloc(8388608);

  k_prep<<<2304, 256, 0, stream>>>(A, B, C, Mt, Tp0, Btc, Ct);

  // expm Taylor-4 (Horner), 3 dependent GEMM phases -> kernel boundaries
  k_taylor<<<16, 256, 0, stream>>>(Mt, Tp0, Tp1, QSh, QSl, Et, 1.0f / 3.0f, 0);
  k_taylor<<<16, 256, 0, stream>>>(Mt, Tp1, Tp0, QSh, QSl, Et, 0.5f, 0);
  k_taylor<<<16, 256, 0, stream>>>(Mt, Tp0, Tp1, QSh, QSl, Et, 1.0f, 1);

  // power stack via log-doubling: QS[d+j] = QS[j] @ QS[d-1]
  for (int d = 1; d <= 8; d <<= 1)
    k_power<<<d * 16, 256, 0, stream>>>(QSh, QSl, d);

  k_gemm_u<<<512, 256, 0, stream>>>(x, Btc, u);
  k_phase1<<<64, 256, 0, stream>>>(u, Et, hs, g0, h0);

  // Kogge-Stone scan over carries: 7 rounds, ping-pong host-side
  {
    const unsigned short* cSh = QSh + 15 * 65536;   // A16^T = QS[15]
    const unsigned short* cSl = QSl + 15 * 65536;
    float* gi = g0;
    float* go = g1;
    for (int rd = 0; rd < 7; ++rd) {
      int rs = 8 << rd;
      int dosq = (rd < 6) ? 1 : 0;
      unsigned short* dh = (rd & 1) ? Sh1 : Sh0;
      unsigned short* dl = (rd & 1) ? Sl1 : Sl0;
      k_scanround<<<dosq ? 272 : 256, 256, 0, stream>>>(gi, go, cSh, cSl, dh, dl, rs, dosq);
      if (dosq) {
        cSh = dh; cSl = dl;
        float* tg = gi; gi = go; go = tg;
      }
    }
  }

  k_carryexp<<<1024, 256, 0, stream>>>(g1, QSh, QSl, hs);
  k_gemm_y<<<dim3(128, 8), 256, 0, stream>>>(hs, Ct, x, D, y);
}